// Round 4
// baseline (92.154 us; speedup 1.0000x reference)
//
#include <hip/hip_runtime.h>
#include <math.h>

// DVS forward: per-batch 6x6 normal-equation build + solve.
// B=64, image 512x640, border 5 -> interior rows [5,507), cols [5,635).
// R3: block-LDS-staged Ids. Block = 4 waves x 4 rows = 16 center rows; stage
// 22 Ids rows x 264 cols to LDS once (1 barrier), then each wave is
// autonomous: 10-row register window + 2 horizontal-halo ds_read_b128 per row
// replace global Ids loads and shuffles. Is/Zinv are direct float4 loads.

namespace {
constexpr int HI = 512, WI = 640, BRD = 5;
constexpr int RPT = 4;                 // center rows per wave
constexpr int WVS = 4;                 // waves per block
constexpr int RB  = RPT * WVS;         // 16 center rows per block
constexpr int TG  = 32;                // ceil(502/16) row tile-groups
constexpr int SEGS = 3;
constexpr int BLK_PER_B = SEGS * TG;   // 96 partials per batch
constexpr int TW = 264;                // staged local cols
constexpr int TR = RB + 6;             // 22 staged rows
constexpr float PXc = 600.0f, PYc = 600.0f, U0c = 320.0f, V0c = 256.0f;
constexpr float G1 = 2047.0f / 8418.0f * 600.0f;   // F*PX (PX==PY)
constexpr float G2 = 913.0f  / 8418.0f * 600.0f;
constexpr float G3 = 112.0f  / 8418.0f * 600.0f;
}

__device__ __forceinline__ float elem(const float4 v, int q) {
    return q == 0 ? v.x : (q == 1 ? v.y : (q == 2 ? v.z : v.w));
}

__global__ __launch_bounds__(256) void dvs_partial(
    const float* __restrict__ Is, const float* __restrict__ Ids,
    const float* __restrict__ Zinv, float* __restrict__ ws)
{
    const int tid  = threadIdx.x;
    const int lane = tid & 63;
    const int wv   = tid >> 6;
    const int b   = blockIdx.x / BLK_PER_B;
    const int rem = blockIdx.x - b * BLK_PER_B;
    const int seg = rem / TG;
    const int tg  = rem - seg * TG;

    const int sbase = (seg == 0) ? -4  : ((seg == 1) ? 196 : 380);
    const int base  = sbase + 4;
    const int lo    = (seg == 0) ? 5   : ((seg == 1) ? 252 : 452);
    const int hi    = (seg == 0) ? 252 : ((seg == 1) ? 452 : 635);
    const int blk_r0 = BRD + tg * RB;            // first center row of block

    const size_t ofs = (size_t)b * (HI * WI);
    const float* __restrict__ Ib = Is   + ofs;
    const float* __restrict__ Db = Ids  + ofs;
    const float* __restrict__ Zb = Zinv + ofs;

    __shared__ float tile[TR][TW];
    __shared__ float red[WVS][28];

    // ---- cooperative Ids staging: 22 rows x 264 cols, float4 chunks ----
    for (int i = tid; i < TR * (TW / 4); i += 256) {
        const int rr = i / (TW / 4);
        const int c4 = i - rr * (TW / 4);
        const int gr = min(blk_r0 - 3 + rr, HI - 1);
        int gc = sbase + c4 * 4;
        gc = max(0, min(gc, WI - 4));
        *(float4*)&tile[rr][c4 * 4] = *(const float4*)(Db + gr * WI + gc);
    }

    const int r0 = blk_r0 + wv * RPT;
    const int c0 = base + (lane << 2);           // global center col
    const int lc = 4 + (lane << 2);              // local center col

    float msk[4], xk[4], opx[4];
#pragma unroll
    for (int q = 0; q < 4; ++q) {
        const int c = c0 + q;
        msk[q] = (c >= lo && c < hi) ? 1.0f : 0.0f;
        xk[q]  = ((float)c - U0c) * (1.0f / PXc);
        opx[q] = 1.0f + xk[q] * xk[q];
    }

    // Is/Zinv: independent global float4 loads, issued up front
    float4 isv[RPT], zvv[RPT];
#pragma unroll
    for (int k = 0; k < RPT; ++k) {
        const int rr = min(r0 + k, HI - 1);
        isv[k] = *(const float4*)(Ib + rr * WI + c0);
        zvv[k] = *(const float4*)(Zb + rr * WI + c0);
    }

    __syncthreads();

    // 10-row vertical register window from LDS
    float4 win[10];
#pragma unroll
    for (int j = 0; j < 10; ++j)
        win[j] = *(const float4*)&tile[wv * RPT + j][lc];

    float acc[27];
#pragma unroll
    for (int t = 0; t < 27; ++t) acc[t] = 0.0f;

#pragma unroll
    for (int k = 0; k < RPT; ++k) {
        const int rc = r0 + k;
        const float rmk = (rc < HI - BRD) ? 1.0f : 0.0f;
        const float4 a0 = win[k], a1 = win[k + 1], a2 = win[k + 2],
                     ct = win[k + 3], a4 = win[k + 4], a5 = win[k + 5],
                     a6 = win[k + 6];
        const float4 lw = *(const float4*)&tile[wv * RPT + k + 3][lc - 4];
        const float4 rw = *(const float4*)&tile[wv * RPT + k + 3][lc + 4];
        const float h[10] = {lw.y, lw.z, lw.w, ct.x, ct.y, ct.z, ct.w,
                             rw.x, rw.y, rw.z};
        const float yv  = ((float)rc - V0c) * (1.0f / PYc);
        const float opy = 1.0f + yv * yv;
        const float4 isV = isv[k], zV = zvv[k];
#pragma unroll
        for (int q = 0; q < 4; ++q) {
            const float m  = msk[q] * rmk;
            const float Ix = (G1 * (h[q + 4] - h[q + 2]) +
                              G2 * (h[q + 5] - h[q + 1]) +
                              G3 * (h[q + 6] - h[q])) * m;
            const float Iy = (G1 * (elem(a4, q) - elem(a2, q)) +
                              G2 * (elem(a5, q) - elem(a1, q)) +
                              G3 * (elem(a6, q) - elem(a0, q))) * m;
            const float Z  = elem(zV, q);
            const float e  = elem(isV, q) - elem(ct, q);
            const float x  = xk[q], xy = x * yv;
            float L[6];
            L[0] = Ix * Z;
            L[1] = Iy * Z;
            L[2] = -(x * Ix + yv * Iy) * Z;
            L[3] = -Ix * xy - opy * Iy;
            L[4] = opx[q] * Ix + Iy * xy;
            L[5] = Iy * x - Ix * yv;
            int t = 0;
#pragma unroll
            for (int i = 0; i < 6; ++i)
#pragma unroll
                for (int j = i; j < 6; ++j)
                    acc[t++] += L[i] * L[j];
#pragma unroll
            for (int i = 0; i < 6; ++i) acc[21 + i] += L[i] * e;
        }
    }

    // wave butterfly reduce (deterministic)
#pragma unroll
    for (int t = 0; t < 27; ++t) {
        float v = acc[t];
        v += __shfl_xor(v, 1);  v += __shfl_xor(v, 2);  v += __shfl_xor(v, 4);
        v += __shfl_xor(v, 8);  v += __shfl_xor(v, 16); v += __shfl_xor(v, 32);
        acc[t] = v;
    }
    float outv = acc[0];
#pragma unroll
    for (int t = 1; t < 27; ++t) if (lane == t) outv = acc[t];

    if (lane < 27) red[wv][lane] = outv;
    __syncthreads();
    if (tid < 27) {
        float s = red[0][tid] + red[1][tid] + red[2][tid] + red[3][tid];
        ws[(size_t)blockIdx.x * 27 + tid] = s;
    }
}

__global__ __launch_bounds__(128) void dvs_solve(
    const float* __restrict__ ws, const float* __restrict__ mu,
    float* __restrict__ out)
{
    const int b = blockIdx.x;
    __shared__ float sd[27][BLK_PER_B + 1];
    for (int i = threadIdx.x; i < BLK_PER_B * 27; i += 128) {
        const int s = i / 27, k = i - s * 27;
        sd[k][s] = ws[((size_t)b * BLK_PER_B + s) * 27 + k];
    }
    __syncthreads();
    __shared__ double hsum[27];
    if (threadIdx.x < 27) {
        double t = 0.0;
        for (int s = 0; s < BLK_PER_B; ++s) t += (double)sd[threadIdx.x][s];
        hsum[threadIdx.x] = t;
    }
    __syncthreads();
    if (threadIdx.x == 0) {
        double A[6][7];
        int k = 0;
        for (int i = 0; i < 6; ++i)
            for (int j = i; j < 6; ++j) { A[i][j] = hsum[k]; A[j][i] = hsum[k]; ++k; }
        const double dm = 1.0 + (double)mu[b];
        for (int i = 0; i < 6; ++i) { A[i][i] *= dm; A[i][6] = hsum[21 + i]; }
        for (int col = 0; col < 6; ++col) {
            int p = col; double best = fabs(A[col][col]);
            for (int r = col + 1; r < 6; ++r) {
                const double vv = fabs(A[r][col]);
                if (vv > best) { best = vv; p = r; }
            }
            if (p != col)
                for (int cc = col; cc < 7; ++cc) {
                    const double t = A[col][cc]; A[col][cc] = A[p][cc]; A[p][cc] = t;
                }
            const double inv = 1.0 / A[col][col];
            for (int r = col + 1; r < 6; ++r) {
                const double f = A[r][col] * inv;
                for (int cc = col + 1; cc < 7; ++cc) A[r][cc] -= f * A[col][cc];
            }
        }
        double xs[6];
        for (int i = 5; i >= 0; --i) {
            double s = A[i][6];
            for (int j = i + 1; j < 6; ++j) s -= A[i][j] * xs[j];
            xs[i] = s / A[i][i];
        }
        for (int i = 0; i < 6; ++i) out[b * 6 + i] = (float)(-xs[i]);
    }
}

extern "C" void kernel_launch(void* const* d_in, const int* in_sizes, int n_in,
                              void* d_out, int out_size, void* d_ws, size_t ws_size,
                              hipStream_t stream)
{
    const float* Is   = (const float*)d_in[0];
    const float* Ids  = (const float*)d_in[1];
    const float* Zinv = (const float*)d_in[2];
    const float* mu   = (const float*)d_in[3];
    const int B = in_sizes[3];
    float* out = (float*)d_out;
    float* ws  = (float*)d_ws;

    dvs_partial<<<B * BLK_PER_B, 256, 0, stream>>>(Is, Ids, Zinv, ws);
    dvs_solve<<<B, 128, 0, stream>>>(ws, mu, out);
}